// Round 2
// 1259.107 us; speedup vs baseline: 1.0168x; 1.0168x over previous
//
#include <hip/hip_runtime.h>
#include <stdint.h>

// Problem: x is [8192, 24576] fp32. out[i,j] = relu(x[i,j]) if x[i,j] is among
// the top-64 of row i (ties -> smaller index), else 0.
//
// One block per row, 512 threads, 48 elements/thread in registers as
// order-preserving uint32 keys.
//
// v2 structure (barrier-minimized):
//  - phase-1 histogram over top 11 bits (2048 bins, LDS atomics)
//  - shfl-based block suffix-scan finds the bin holding rank 64
//    (2 barriers, no tree, no serial descent)
//  - FAST PATH (Cnt = candidates at/above that bin <= 512; ~152 expected for
//    N(0,1) rows): gather packed (key<<32)|~idx candidates to LDS, exact rank
//    via broadcast compare loop -> rank-63 candidate IS the 64th element,
//    giving exact threshold key + tie index cutoff. Phases 2/3 + tie path
//    skipped entirely.
//  - FALLBACK (exact, any input): original 3-phase radix + index-tie select,
//    with the tree replaced by the same scan_select.

#define ROWLEN   24576
#define TPB      512
#define CHUNKS   12            // ROWLEN / 4 / TPB
#define ELEMS    48            // CHUNKS * 4
#define TOPK     64
#define CAND_CAP 512

typedef float  fx4 __attribute__((ext_vector_type(4)));   // nontemporal-compatible

__device__ __forceinline__ unsigned enc_key(float f) {
    unsigned u = __float_as_uint(f);
    // monotonic map: negative -> ~u, positive -> u | signbit
    return (u & 0x80000000u) ? ~u : (u | 0x80000000u);
}

// Block-wide rank select over hist[2048]. Scans bins 2047->0 (largest_first)
// or 0->2047 (smallest_first); finds bin where running count reaches `rank`.
// Each thread owns 4 consecutive bins; within-wave shfl scan + 8 wave sums.
// 2 barriers, no serial section. Must be called from block-uniform flow.
__device__ void scan_select(const unsigned* hist, unsigned* wsum, int tid,
                            bool smallest_first, unsigned rank,
                            volatile unsigned* s_bin, volatile unsigned* s_rank) {
    const uint4 h4 = ((const uint4*)hist)[tid];
    unsigned h[4] = {h4.x, h4.y, h4.z, h4.w};
    unsigned s = h[0] + h[1] + h[2] + h[3];
    int lane = tid & 63, wave = tid >> 6;
    unsigned run = s;   // inclusive scan in the scan direction
    if (smallest_first) {
#pragma unroll
        for (int off = 1; off < 64; off <<= 1) {
            unsigned v = __shfl_up(run, off);
            if (lane >= off) run += v;
        }
    } else {
#pragma unroll
        for (int off = 1; off < 64; off <<= 1) {
            unsigned v = __shfl_down(run, off);
            if (lane + off < 64) run += v;
        }
    }
    if (lane == (smallest_first ? 63 : 0)) wsum[wave] = run;
    __syncthreads();
    unsigned wexcl = 0;
    if (smallest_first) { for (int w = 0; w < wave; ++w) wexcl += wsum[w]; }
    else                { for (int w = wave + 1; w < 8; ++w) wexcl += wsum[w]; }
    unsigned A = wexcl + (run - s);   // count strictly before this thread's bins
    if (A < rank && rank <= A + s) {  // exactly one thread crosses
        unsigned cum = A;
        if (smallest_first) {
#pragma unroll
            for (int b = 0; b < 4; ++b) {
                if (cum + h[b] >= rank) { *s_bin = (unsigned)(4 * tid + b); *s_rank = rank - cum; break; }
                cum += h[b];
            }
        } else {
#pragma unroll
            for (int b = 3; b >= 0; --b) {
                if (cum + h[b] >= rank) { *s_bin = (unsigned)(4 * tid + b); *s_rank = rank - cum; break; }
                cum += h[b];
            }
        }
    }
    __syncthreads();
}

__device__ __forceinline__ float out_val(unsigned k, unsigned idx,
                                         unsigned Tkey, unsigned C) {
    bool sel = (k > Tkey) || (k == Tkey && idx <= C);
    // positive originals have key > 0x80000000 (0x80000000 == +0.0 -> relu 0)
    return (sel && k > 0x80000000u) ? __uint_as_float(k ^ 0x80000000u) : 0.0f;
}

__global__ __launch_bounds__(TPB, 4)
void topk_scatter_kernel(const float* __restrict__ x, float* __restrict__ out,
                         int nrows) {
    __shared__ __align__(16) unsigned hist[2048];
    __shared__ unsigned wsum[8];
    __shared__ unsigned s_bin, s_rank, s_cnt, s_C, s_Tkey;
    __shared__ unsigned long long cand[CAND_CAP];
    __shared__ unsigned cand16[16];

    int row = blockIdx.x;
    if (row >= nrows) return;
    int tid = threadIdx.x;

    const fx4* rowp = (const fx4*)(x + (size_t)row * ROWLEN);
    fx4*       outp = (fx4*)(out + (size_t)row * ROWLEN);

    // ---- single HBM read pass: keys into registers (non-temporal: no reuse)
    unsigned keys[ELEMS];
#pragma unroll
    for (int c = 0; c < CHUNKS; ++c) {
        fx4 v = __builtin_nontemporal_load(&rowp[c * TPB + tid]);
        keys[4 * c + 0] = enc_key(v.x);
        keys[4 * c + 1] = enc_key(v.y);
        keys[4 * c + 2] = enc_key(v.z);
        keys[4 * c + 3] = enc_key(v.w);
    }

    // ---- phase 1: histogram of top 11 bits
    for (int i = tid; i < 2048; i += TPB) hist[i] = 0;
    if (tid == 0) s_cnt = 0;
    __syncthreads();
#pragma unroll
    for (int e = 0; e < ELEMS; ++e) atomicAdd(&hist[keys[e] >> 21], 1u);
    __syncthreads();
    scan_select(hist, wsum, tid, false, TOPK, &s_bin, &s_rank);
    unsigned B1 = s_bin, R1 = s_rank;
    unsigned binCnt = hist[B1];                // safe: hist untouched since barrier
    unsigned Cnt = (TOPK - R1) + binCnt;       // # keys with (key>>21) >= B1, exact

    unsigned Tkey;
    unsigned C = 0xFFFFFFFFu;                  // index cutoff among key-ties

    if (Cnt <= CAND_CAP) {
        // ================= FAST PATH =================
        // Gather all candidates (exactly Cnt of them) as packed 64-bit sort
        // keys: high 32 = key (desc), low 32 = ~idx (so bigger packed == better,
        // ties resolved toward smaller index — exactly jax.lax.top_k order).
#pragma unroll
        for (int e = 0; e < ELEMS; ++e) {
            if ((keys[e] >> 21) >= B1) {
                unsigned idx = ((unsigned)((e / 4) * TPB + tid)) * 4u + (e & 3);
                unsigned p = atomicAdd(&s_cnt, 1u);     // p < Cnt <= CAND_CAP
                cand[p] = ((unsigned long long)keys[e] << 32) | (unsigned)(~idx);
            }
        }
        __syncthreads();
        if (tid < (int)Cnt) {
            unsigned long long mine = cand[tid];
            unsigned r = 0;
            for (unsigned j = 0; j < Cnt; ++j) r += (cand[j] > mine);  // LDS broadcast
            if (r == TOPK - 1) {               // the exact 64th element
                s_Tkey = (unsigned)(mine >> 32);
                s_C    = ~(unsigned)mine;
            }
        }
        __syncthreads();
        Tkey = s_Tkey;
        C    = s_C;
    } else {
        // ================= FALLBACK (exact, rare) =================
        __syncthreads();                       // protect binCnt reads vs clear
        // phase 2: bits 20..10 among keys with top11 == B1
        for (int i = tid; i < 2048; i += TPB) hist[i] = 0;
        __syncthreads();
#pragma unroll
        for (int e = 0; e < ELEMS; ++e)
            if ((keys[e] >> 21) == B1) atomicAdd(&hist[(keys[e] >> 10) & 0x7FFu], 1u);
        __syncthreads();
        scan_select(hist, wsum, tid, false, R1, &s_bin, &s_rank);
        unsigned B2 = s_bin, R2 = s_rank;

        // phase 3: low 10 bits
        unsigned pref22 = (B1 << 11) | B2;
        for (int i = tid; i < 2048; i += TPB) hist[i] = 0;
        __syncthreads();
#pragma unroll
        for (int e = 0; e < ELEMS; ++e)
            if ((keys[e] >> 10) == pref22) atomicAdd(&hist[keys[e] & 0x3FFu], 1u);
        __syncthreads();
        scan_select(hist, wsum, tid, false, R2, &s_bin, &s_rank);
        unsigned B3 = s_bin, R3 = s_rank;
        unsigned eqcnt = hist[B3];
        Tkey = (B1 << 21) | (B2 << 10) | B3;

        if (R3 < eqcnt) {
            // partial-tie: need R3-th smallest index among key == Tkey
            __syncthreads();                   // protect eqcnt reads vs clear
            for (int i = tid; i < 2048; i += TPB) hist[i] = 0;
            if (tid == 0) s_cnt = 0;
            __syncthreads();
#pragma unroll
            for (int e = 0; e < ELEMS; ++e) {
                if (keys[e] == Tkey) {
                    unsigned idx = ((unsigned)((e / 4) * TPB + tid)) * 4u + (e & 3);
                    atomicAdd(&hist[idx >> 4], 1u);   // idx < 24576 -> bin < 1536
                }
            }
            __syncthreads();
            scan_select(hist, wsum, tid, true, R3, &s_bin, &s_rank);
            unsigned B4 = s_bin, r4 = s_rank;
#pragma unroll
            for (int e = 0; e < ELEMS; ++e) {
                if (keys[e] == Tkey) {
                    unsigned idx = ((unsigned)((e / 4) * TPB + tid)) * 4u + (e & 3);
                    if ((idx >> 4) == B4) {
                        unsigned p = atomicAdd(&s_cnt, 1u);
                        if (p < 16u) cand16[p] = idx;  // <=16 distinct indices/bin
                    }
                }
            }
            __syncthreads();
            if (tid == 0) {
                unsigned n = s_cnt; if (n > 16u) n = 16u;
                for (unsigned a = 0; a + 1 < n; ++a)   // tiny selection sort
                    for (unsigned b = a + 1; b < n; ++b)
                        if (cand16[b] < cand16[a]) { unsigned t = cand16[a]; cand16[a] = cand16[b]; cand16[b] = t; }
                s_C = cand16[r4 - 1];
            }
            __syncthreads();
            C = s_C;
        }
    }

    // ---- single HBM write pass (non-temporal: write-once, never re-read)
#pragma unroll
    for (int c = 0; c < CHUNKS; ++c) {
        unsigned base = ((unsigned)(c * TPB + tid)) * 4u;
        fx4 o;
        o.x = out_val(keys[4 * c + 0], base + 0u, Tkey, C);
        o.y = out_val(keys[4 * c + 1], base + 1u, Tkey, C);
        o.z = out_val(keys[4 * c + 2], base + 2u, Tkey, C);
        o.w = out_val(keys[4 * c + 3], base + 3u, Tkey, C);
        __builtin_nontemporal_store(o, &outp[c * TPB + tid]);
    }
}

extern "C" void kernel_launch(void* const* d_in, const int* in_sizes, int n_in,
                              void* d_out, int out_size, void* d_ws, size_t ws_size,
                              hipStream_t stream) {
    const float* x = (const float*)d_in[0];
    float* out = (float*)d_out;
    int nrows = in_sizes[0] / ROWLEN;   // 8192
    topk_scatter_kernel<<<nrows, TPB, 0, stream>>>(x, out, nrows);
}